// Round 17
// baseline (296.249 us; speedup 1.0000x reference)
//
#include <hip/hip_runtime.h>
#include <hip/hip_bf16.h>
#include <math.h>

#define Tn 8
#define Hn 32
#define Wn 32
#define Pn 8192      // Tn*Hn*Wn
#define Cn 256
#define CINn 128
#define NTAP 147     // 3*7*7
#define PADW 40      // bf16 elems per padded plane row (80B -> 2-way banks, free)

typedef short s8v __attribute__((ext_vector_type(8)));   // 8 x bf16 (4 VGPRs)
typedef float f4v __attribute__((ext_vector_type(4)));   // MFMA acc
typedef __hip_bfloat16 bf16;

__device__ __forceinline__ float gelu_f(float v) {
    return 0.5f * v * (1.0f + tanhf(0.7978845608028654f * (v + 0.044715f * v * v * v)));
}
__device__ __forceinline__ float bf2f(short s) {
    return __uint_as_float(((unsigned)(unsigned short)s) << 16);
}

// async global->LDS, 16B per lane (dest = wave-uniform base + lane*16)
__device__ __forceinline__ void gload_lds16(const bf16* g, bf16* l) {
    __builtin_amdgcn_global_load_lds(
        (const __attribute__((address_space(1))) void*)g,
        (__attribute__((address_space(3))) void*)l, 16, 0, 0);
}

// ---- chunked operand layouts (staging-coalesced): chunk = 8 bf16 = 16B ----
// A'[m>>7][k>>6][ ((k>>3)&7)*128 + (m&127) ][k&7]   (BM=128 fixed)
__device__ __forceinline__ size_t caddrA(int K, int m, int k) {
    return ((size_t)(m >> 7) * (K >> 6) + (k >> 6)) * 8192 +
           (size_t)((((k >> 3) & 7) * 128 + (m & 127)) * 8 + (k & 7));
}
// B'[n/BN][k>>6][ ((k>>3)&7)*BN + n%BN ][k&7]
__device__ __forceinline__ size_t caddrB(int K, int BN, int n, int k) {
    return ((size_t)(n / BN) * (K >> 6) + (k >> 6)) * (size_t)(BN * 64) +
           (size_t)((((k >> 3) & 7) * BN + (n % BN)) * 8 + (k & 7));
}

// ---------------- ALL weight transposes+casts + video cast in ONE dispatch ----------------
// z=0: conv_w -> cwT (B-chunked, BN=32, K=128); z=1..3: w1[i] -> w1T (BN=64, K=256);
// z=4..6: w2[i] -> w2T (BN=32, K=1024); z=7: video -> vb (A-chunked, K=128).
__global__ __launch_bounds__(256) void tcast_all_k(
        const float* __restrict__ convw, const float* __restrict__ w1,
        const float* __restrict__ w2, const float* __restrict__ video,
        bf16* __restrict__ cwT, bf16* __restrict__ w1T, bf16* __restrict__ w2T,
        bf16* __restrict__ vb) {
    const int z = blockIdx.z;
    const int tid = (int)threadIdx.x;
    if (z == 7) {   // video cast -> A-chunked vb
        const int bx = (int)blockIdx.y * 32 + (int)blockIdx.x;
        const int i = bx * 256 + tid;
        const int p = i >> 5, c0 = (i & 31) * 4;
        const float4 v = ((const float4*)video)[i];
        const size_t a0 = caddrA(CINn, p, c0);
        vb[a0 + 0] = __float2bfloat16(v.x);
        vb[a0 + 1] = __float2bfloat16(v.y);
        vb[a0 + 2] = __float2bfloat16(v.z);
        vb[a0 + 3] = __float2bfloat16(v.w);
        return;
    }
    const float* in;
    bf16* out;
    int R, C, bn;
    if (z == 0)      { in = convw;                       out = cwT;                          R = CINn; C = Cn;   bn = 32; }
    else if (z < 4)  { const int i = z - 1;
                       in = w1 + (size_t)i * Cn * 1024;  out = w1T + (size_t)i * 1024 * Cn;  R = Cn;   C = 1024; bn = 64; }
    else             { const int i = z - 4;
                       in = w2 + (size_t)i * 1024 * Cn;  out = w2T + (size_t)i * Cn * 1024;  R = 1024; C = Cn;   bn = 32; }
    if ((int)blockIdx.x >= (C >> 5) || (int)blockIdx.y >= (R >> 5)) return;

    __shared__ float tile[32][33];
    const int tx = tid & 31, ty = tid >> 5;
    const int rb = blockIdx.y << 5, cb = blockIdx.x << 5;
#pragma unroll
    for (int p = 0; p < 4; ++p)
        tile[ty + p * 8][tx] = in[(size_t)(rb + ty + p * 8) * C + cb + tx];
    __syncthreads();
#pragma unroll
    for (int p = 0; p < 4; ++p)
        out[caddrB(R, bn, cb + ty + p * 8, rb + tx)] = __float2bfloat16(tile[tx][ty + p * 8]);
}

// ---------------- bf16 MFMA GEMM: C[M,N] = f(A @ Wt^T + bias) ----------------
// BK=128: two 64-k chunk-groups staged per barrier (halves barrier pairs vs BK=64).
// B always B'-chunked. A: ACH=1 -> A'-chunked, ACH=0 -> linear [m][K].
// MODE 0: Cf = v ; MODE 1: Cb = bf16(gelu(v)) A'-chunked ; MODE 2: Cf += v.
// Cpl: optional bf16 plane copy Cpl[c][p]. Requires K % 128 == 0.
template <int BN, int MODE, int ACH>
__global__ __launch_bounds__(256) void gemm_bf16_k(
        const bf16* __restrict__ A, const bf16* __restrict__ Wt,
        const float* __restrict__ bias, float* __restrict__ Cf,
        bf16* __restrict__ Cb, bf16* __restrict__ Cpl, int M, int N, int K) {
    constexpr int BM = 128;
    constexpr int NW = BN / 2;
    constexpr int NF = BN / 32;
    constexpr int BLOADS = (BN * 8) / 256;    // per 64-k group: 1 / 2 / 4
    __shared__ s8v As[16 * BM];               // 2 groups x 8 k8-chunks x BM
    __shared__ s8v Bs[16 * BN];

    const int tid = (int)threadIdx.x;
    const int lane = tid & 63, wid = tid >> 6;
    const int wm = wid & 1, wn = wid >> 1;
    const int l15 = lane & 15, l4 = lane >> 4;
    const int m0 = blockIdx.y * BM;
    const int n0 = blockIdx.x * BN;

    f4v acc[4][NF];
#pragma unroll
    for (int i = 0; i < 4; ++i)
#pragma unroll
        for (int j = 0; j < NF; ++j)
#pragma unroll
            for (int r = 0; r < 4; ++r) acc[i][j][r] = 0.f;

    const bf16* Ach = A + ((size_t)(m0 >> 7) * (K >> 6)) * 8192;          // ACH=1
    const bf16* Aln[4];                                                   // ACH=0
    if (ACH == 0) {
#pragma unroll
        for (int j = 0; j < 4; ++j) {
            const int cid = j * 256 + tid;
            Aln[j] = A + (size_t)(m0 + (cid & (BM - 1))) * K + (cid / BM) * 8;
        }
    }
    const bf16* Bch = Wt + ((size_t)(n0 / BN) * (K >> 6)) * (size_t)(BN * 64);

    for (int kb = 0; kb < K; kb += 128) {
        const int kc = kb >> 6;
#pragma unroll
        for (int u = 0; u < 2; ++u) {
            if (ACH == 1) {
#pragma unroll
                for (int j = 0; j < 4; ++j)
                    gload_lds16(Ach + (size_t)(kc + u) * 8192 + (j * 256 + tid) * 8,
                                (bf16*)&As[u * 1024 + j * 256 + tid]);
            } else {
#pragma unroll
                for (int j = 0; j < 4; ++j)
                    gload_lds16(Aln[j] + kb + u * 64,
                                (bf16*)&As[u * 1024 + j * 256 + tid]);
            }
#pragma unroll
            for (int j = 0; j < BLOADS; ++j)
                gload_lds16(Bch + (size_t)(kc + u) * (BN * 64) + (j * 256 + tid) * 8,
                            (bf16*)&Bs[u * (8 * BN) + j * 256 + tid]);
        }
        __syncthreads();

#pragma unroll
        for (int ksl = 0; ksl < 4; ++ksl) {
            const int u = ksl >> 1, ks = ksl & 1;
            s8v af[4], bfr[NF];
#pragma unroll
            for (int i = 0; i < 4; ++i)
                af[i] = As[u * 1024 + (ks * 4 + l4) * BM + wm * 64 + i * 16 + l15];
#pragma unroll
            for (int j = 0; j < NF; ++j)
                bfr[j] = Bs[u * (8 * BN) + (ks * 4 + l4) * BN + wn * NW + j * 16 + l15];
#pragma unroll
            for (int i = 0; i < 4; ++i)
#pragma unroll
                for (int j = 0; j < NF; ++j)
                    acc[i][j] = __builtin_amdgcn_mfma_f32_16x16x32_bf16(
                        af[i], bfr[j], acc[i][j], 0, 0, 0);
        }
        __syncthreads();
    }

#pragma unroll
    for (int i = 0; i < 4; ++i) {
        const int rbase = m0 + wm * 64 + i * 16 + l4 * 4;
#pragma unroll
        for (int j = 0; j < NF; ++j) {
            const int col = n0 + wn * NW + j * 16 + l15;
            const float bv = bias[col];
#pragma unroll
            for (int r = 0; r < 4; ++r) {
                const size_t idx = (size_t)(rbase + r) * N + col;
                float v = acc[i][j][r] + bv;
                if (MODE == 0) Cf[idx] = v;
                if (MODE == 1) Cb[caddrA(N, rbase + r, col)] = __float2bfloat16(gelu_f(v));
                if (MODE == 2) { v += Cf[idx]; Cf[idx] = v; }
                if (MODE != 1 && Cpl != nullptr)
                    Cpl[(size_t)col * Pn + rbase + r] = __float2bfloat16(v);
            }
        }
    }
}

// ---------------- fused 8-iteration depthwise circular conv SSM via MFMA ----------------
#define CLOADS(AS, BS0, BS1, body) do {                                       \
    const int bb_ = (body);                                                   \
    const int kt_ = bb_ < 7 ? 0 : (bb_ < 14 ? 1 : 2);                         \
    const int kh_ = bb_ - kt_ * 7;                                            \
    BS0 = *(const s8v*)&tw[bb_][u0][0];                                       \
    BS1 = *(const s8v*)&tw[bb_][u1][0];                                       \
    _Pragma("unroll")                                                         \
    for (int i_ = 0; i_ < 2; ++i_) {                                          \
        const int tp_ = (tout[i_] - kt_ + 9) & 7;                             \
        const int hin_ = (hl[i_] + 35 - kh_) & 31;                            \
        AS[i_] = *(const s8v*)&pl[(tp_ * 32 + hin_) * PADW + aoff];           \
    }                                                                         \
} while (0)

#define CMFMA(AS, BS0, BS1) do {                                              \
    _Pragma("unroll")                                                         \
    for (int i_ = 0; i_ < 2; ++i_) {                                          \
        acc[i_][0] = __builtin_amdgcn_mfma_f32_16x16x32_bf16(AS[i_], BS0, acc[i_][0], 0, 0, 0); \
        acc[i_][1] = __builtin_amdgcn_mfma_f32_16x16x32_bf16(AS[i_], BS1, acc[i_][1], 0, 0, 0); \
    }                                                                         \
} while (0)

__global__ __launch_bounds__(512) void conv_ssm_k(
        const bf16* __restrict__ xplb,  // [C][8192] bf16 (channel planes)
        const float* __restrict__ Ak,   // [C][147]
        const float* __restrict__ Bk,   // [C][147]
        bf16* __restrict__ hpo) {       // [C][8192] bf16
    __shared__ __align__(16) bf16 Pl[2][256 * PADW];   // 40 KB
    __shared__ __align__(16) bf16 Tw[2][21][32][8];    // 21 KB
    __shared__ float wtap[2][NTAP];

    const int c = blockIdx.x;
    const int tid = (int)threadIdx.x;
    const int lane = tid & 63, wv = tid >> 6;
    const int l15 = lane & 15, l4 = lane >> 4;

    if (tid < NTAP) {
        wtap[0][tid] = Bk[(size_t)c * NTAP + tid];
        wtap[1][tid] = 0.9f * tanhf(Ak[(size_t)c * NTAP + tid]);
    }
    {   // stage x plane (bf16), padded rows
        const s8v* src = (const s8v*)(xplb + (size_t)c * Pn);
#pragma unroll
        for (int j = 0; j < 2; ++j) {
            const int g = j * 512 + tid;
            *(s8v*)&Pl[0][(g >> 2) * PADW + (g & 3) * 8] = src[g];
        }
    }
    __syncthreads();
    for (int e = tid; e < 2 * 21 * 32; e += 512) {
        const int sel = e / 672, rem = e % 672;
        const int body = rem >> 5, u = rem & 31;
        const float* tp = &wtap[sel][body * 7];
        bf16 row[8];
#pragma unroll
        for (int j = 0; j < 8; ++j) {
            const int kw = (u - j) & 31;
            row[j] = __float2bfloat16((kw < 7) ? tp[kw] : 0.f);
        }
        *(s8v*)&Tw[sel][body][u][0] = *(const s8v*)row;
    }

    const int u0 = (l15 - l4 * 8 + 3) & 31;
    const int u1 = (l15 + 16 - l4 * 8 + 3) & 31;
    int tout[2], hl[2];
#pragma unroll
    for (int i = 0; i < 2; ++i) {
        const int f = wv * 2 + i;
        tout[i] = f >> 1;
        hl[i] = ((f & 1) << 4) + l15;
    }
    const int aoff = l4 * 8;

    float hsum[16];
#pragma unroll
    for (int i = 0; i < 16; ++i) hsum[i] = 0.f;
    __syncthreads();

#pragma unroll 1
    for (int it = 0; it < 8; ++it) {
        const bf16* pl = Pl[it & 1];
        bf16* pd = Pl[(it + 1) & 1];
        const bf16 (*tw)[32][8] = Tw[(it == 0) ? 0 : 1];

        f4v acc[2][2];
#pragma unroll
        for (int i = 0; i < 2; ++i)
#pragma unroll
            for (int hf = 0; hf < 2; ++hf)
#pragma unroll
                for (int r = 0; r < 4; ++r) acc[i][hf][r] = 0.f;

        s8v a0[2], a1[2], b00, b01, b10, b11;
        CLOADS(a0, b00, b01, 0);
#pragma unroll 1
        for (int b = 0; b < 20; b += 2) {
            CLOADS(a1, b10, b11, b + 1);
            CMFMA(a0, b00, b01);
            CLOADS(a0, b00, b01, b + 2);
            CMFMA(a1, b10, b11);
        }
        CMFMA(a0, b00, b01);

#pragma unroll
        for (int i = 0; i < 2; ++i) {
            const int rbase = (wv * 2 + i) * 16 + l4 * 4;
#pragma unroll
            for (int hf = 0; hf < 2; ++hf) {
                const int col = l15 + hf * 16;
#pragma unroll
                for (int r = 0; r < 4; ++r) {
                    const float v = acc[i][hf][r];
                    hsum[i * 8 + hf * 4 + r] += v;
                    if (it < 7) pd[(rbase + r) * PADW + col] = __float2bfloat16(v);
                }
            }
        }
        __syncthreads();
    }

    bf16* o = hpo + (size_t)c * Pn;
#pragma unroll
    for (int i = 0; i < 2; ++i) {
        const int rbase = (wv * 2 + i) * 16 + l4 * 4;
#pragma unroll
        for (int hf = 0; hf < 2; ++hf)
#pragma unroll
            for (int r = 0; r < 4; ++r)
                o[(rbase + r) * 32 + l15 + hf * 16] = __float2bfloat16(hsum[i * 8 + hf * 4 + r]);
    }
}

// ---------------- LN from bf16 plane-layout h: x += LN(h)*s + b ; emit xb bf16 ----------------
__global__ __launch_bounds__(256) void ln_res_plane_k(
        const bf16* __restrict__ hpl,    // [256][8192] bf16
        const float* __restrict__ scale, const float* __restrict__ bias,
        float* __restrict__ x,           // [8192][256] in/out
        bf16* __restrict__ xb) {         // [8192][256] linear (w1 A, ACH=0)
    __shared__ float tile[256][33];
    __shared__ float red[2][32][9];
    __shared__ float mus[32], rss[32];
    const int tid = (int)threadIdx.x;
    const int p0 = blockIdx.x << 5;

    {   // load: thread = channel (32 bf16 = 4 x s8v)
        const bf16* src = hpl + (size_t)tid * Pn + p0;
#pragma unroll
        for (int j = 0; j < 32; j += 8) {
            const s8v v = *(const s8v*)(src + j);
#pragma unroll
            for (int e = 0; e < 8; ++e) tile[tid][j + e] = bf2f(v[e]);
        }
    }
    __syncthreads();
    {   // partial reduce: tid = g*32 + p
        const int p = tid & 31, g = tid >> 5;
        float s = 0.f, ss = 0.f;
#pragma unroll
        for (int ci = 0; ci < 32; ++ci) {
            const float v = tile[g * 32 + ci][p];
            s += v; ss += v * v;
        }
        red[0][p][g] = s; red[1][p][g] = ss;
    }
    __syncthreads();
    if (tid < 32) {
        float s = 0.f, ss = 0.f;
#pragma unroll
        for (int g = 0; g < 8; ++g) { s += red[0][tid][g]; ss += red[1][tid][g]; }
        const float mu = s * (1.0f / 256.0f);
        const float var = ss * (1.0f / 256.0f) - mu * mu;
        mus[tid] = mu;
        rss[tid] = rsqrtf(var + 1e-6f);
    }
    __syncthreads();
    {   // apply: thread = channel, coalesced across lanes per point
        const int cch = tid;
        const float sc = scale[cch], bi = bias[cch];
#pragma unroll 4
        for (int j = 0; j < 32; ++j) {
            const size_t idx = (size_t)(p0 + j) * Cn + cch;
            const float normed = (tile[cch][j] - mus[j]) * rss[j] * sc + bi;
            const float xv = x[idx] + normed;
            x[idx] = xv;
            xb[idx] = __float2bfloat16(xv);
        }
    }
}

// ---------------- feat partial sums over (h,w) ----------------
__global__ void feat_part_k(const float* __restrict__ x, float* __restrict__ part) {
    const int t = blockIdx.x, sgm = blockIdx.y;
    const int c = (int)threadIdx.x;
    float acc = 0.f;
    const float* xp_ = x + ((size_t)t * 1024 + sgm * 128) * Cn + c;
    for (int p = 0; p < 128; ++p) acc += xp_[(size_t)p * Cn];
    part[(t * 8 + sgm) * Cn + c] = acc;
}

// ---------------- heads (folds the feat 8-way reduce) ----------------
__global__ __launch_bounds__(256) void heads_k(
        const float* __restrict__ part, const float* __restrict__ qp,
        const float* __restrict__ traj_w, const float* __restrict__ traj_b,
        const float* __restrict__ occ_w, const float* __restrict__ occ_b,
        float* __restrict__ out) {
    __shared__ float fs[Tn * Cn];
    __shared__ float proj[Tn][3];
    const int tid = (int)threadIdx.x;
    for (int i = tid; i < Tn * Cn; i += 256) {
        const int t = i >> 8, c = i & 255;
        float s = 0.f;
#pragma unroll
        for (int j = 0; j < 8; ++j) s += part[(t * 8 + j) * Cn + c];
        fs[i] = s * (1.0f / 1024.0f);
    }
    __syncthreads();
    if (tid < 24) {
        const int t = tid / 3, j = tid % 3;
        float s = 0.f;
        for (int c = 0; c < Cn; ++c) {
            const float w = (j < 2) ? traj_w[c * 2 + j] : occ_w[c];
            s += fs[t * Cn + c] * w;
        }
        s += (j < 2) ? traj_b[j] : occ_b[0];
        proj[t][j] = s;
    }
    __syncthreads();
    const int n = tid;
#pragma unroll
    for (int t = 0; t < Tn; ++t) {
        out[(n * Tn + t) * 2 + 0] = proj[t][0] + qp[n * 3 + 1];
        out[(n * Tn + t) * 2 + 1] = proj[t][1] + qp[n * 3 + 2];
        out[4096 + n * Tn + t] = 1.0f / (1.0f + expf(-proj[t][2]));
    }
}

extern "C" void kernel_launch(void* const* d_in, const int* in_sizes, int n_in,
                              void* d_out, int out_size, void* d_ws, size_t ws_size,
                              hipStream_t stream) {
    const float* video = (const float*)d_in[0];
    const float* qp    = (const float*)d_in[1];
    const float* convw = (const float*)d_in[2];
    const float* convb = (const float*)d_in[3];
    const float* Ak    = (const float*)d_in[4];
    const float* Bk    = (const float*)d_in[5];
    const float* ln_s  = (const float*)d_in[6];
    const float* ln_b  = (const float*)d_in[7];
    const float* w1    = (const float*)d_in[8];
    const float* b1    = (const float*)d_in[9];
    const float* w2    = (const float*)d_in[10];
    const float* b2    = (const float*)d_in[11];
    const float* tw    = (const float*)d_in[12];
    const float* tb    = (const float*)d_in[13];
    const float* ow    = (const float*)d_in[14];
    const float* ob    = (const float*)d_in[15];

    char* wsb = (char*)d_ws;
    float* x    = (float*)wsb;           wsb += (size_t)Pn * Cn * 4;
    bf16*  hpl  = (bf16*)wsb;            wsb += (size_t)Pn * Cn * 2;
    bf16*  xplb = (bf16*)wsb;            wsb += (size_t)Pn * Cn * 2;
    bf16*  xb   = (bf16*)wsb;            wsb += (size_t)Pn * Cn * 2;
    bf16*  mb   = (bf16*)wsb;            wsb += (size_t)Pn * 1024 * 2;
    bf16*  vb   = (bf16*)wsb;            wsb += (size_t)Pn * CINn * 2;
    bf16*  cwT  = (bf16*)wsb;            wsb += (size_t)Cn * CINn * 2;
    bf16*  w1T  = (bf16*)wsb;            wsb += (size_t)3 * 1024 * Cn * 2;
    bf16*  w2T  = (bf16*)wsb;            wsb += (size_t)3 * Cn * 1024 * 2;
    float* part = (float*)wsb;           wsb += (size_t)64 * Cn * 4;

    tcast_all_k<<<dim3(32, 32, 8), 256, 0, stream>>>(convw, w1, w2, video,
                                                     cwT, w1T, w2T, vb);

    // x = video @ conv_w + b ; also emit bf16 planes for conv input
    gemm_bf16_k<32, 0, 1><<<dim3(Cn / 32, Pn / 128), 256, 0, stream>>>(
        vb, cwT, convb, x, nullptr, xplb, Pn, Cn, CINn);

    for (int i = 0; i < 3; ++i) {
        conv_ssm_k<<<Cn, 512, 0, stream>>>(xplb, Ak + (size_t)i * Cn * NTAP,
                                           Bk + (size_t)i * Cn * NTAP, hpl);
        ln_res_plane_k<<<Pn / 32, 256, 0, stream>>>(hpl, ln_s + i * Cn,
                                                    ln_b + i * Cn, x, xb);
        // m = gelu(xb @ w1)  (A linear, B chunked; mb written A-chunked for w2)
        gemm_bf16_k<64, 1, 0><<<dim3(1024 / 64, Pn / 128), 256, 0, stream>>>(
            xb, w1T + (size_t)i * 1024 * Cn, b1 + (size_t)i * 1024, nullptr, mb,
            nullptr, Pn, 1024, Cn);
        // x += m @ w2  (A chunked, B chunked)
        gemm_bf16_k<32, 2, 1><<<dim3(Cn / 32, Pn / 128), 256, 0, stream>>>(
            mb, w2T + (size_t)i * Cn * 1024, b2 + (size_t)i * Cn, x, nullptr,
            (i < 2) ? xplb : nullptr, Pn, Cn, 1024);
    }

    feat_part_k<<<dim3(Tn, 8), 256, 0, stream>>>(x, part);
    heads_k<<<1, 256, 0, stream>>>(part, qp, tw, tb, ow, ob, (float*)d_out);
}

// Round 18
// 293.615 us; speedup vs baseline: 1.0090x; 1.0090x over previous
//
#include <hip/hip_runtime.h>
#include <hip/hip_bf16.h>
#include <math.h>

#define Tn 8
#define Hn 32
#define Wn 32
#define Pn 8192      // Tn*Hn*Wn
#define Cn 256
#define CINn 128
#define NTAP 147     // 3*7*7
#define PADW 40      // bf16 elems per padded plane row (80B -> 2-way banks, free)

typedef short s8v __attribute__((ext_vector_type(8)));   // 8 x bf16 (4 VGPRs)
typedef float f4v __attribute__((ext_vector_type(4)));   // MFMA acc
typedef __hip_bfloat16 bf16;

__device__ __forceinline__ float gelu_f(float v) {
    return 0.5f * v * (1.0f + tanhf(0.7978845608028654f * (v + 0.044715f * v * v * v)));
}

// async global->LDS, 16B per lane (dest = wave-uniform base + lane*16)
__device__ __forceinline__ void gload_lds16(const bf16* g, bf16* l) {
    __builtin_amdgcn_global_load_lds(
        (const __attribute__((address_space(1))) void*)g,
        (__attribute__((address_space(3))) void*)l, 16, 0, 0);
}

// ---- chunked operand layouts (staging-coalesced): chunk = 8 bf16 = 16B ----
// A'[m>>7][k>>6][ ((k>>3)&7)*128 + (m&127) ][k&7]   (BM=128 fixed)
__device__ __forceinline__ size_t caddrA(int K, int m, int k) {
    return ((size_t)(m >> 7) * (K >> 6) + (k >> 6)) * 8192 +
           (size_t)((((k >> 3) & 7) * 128 + (m & 127)) * 8 + (k & 7));
}
// B'[n/BN][k>>6][ ((k>>3)&7)*BN + n%BN ][k&7]
__device__ __forceinline__ size_t caddrB(int K, int BN, int n, int k) {
    return ((size_t)(n / BN) * (K >> 6) + (k >> 6)) * (size_t)(BN * 64) +
           (size_t)((((k >> 3) & 7) * BN + (n % BN)) * 8 + (k & 7));
}

// ---------------- ALL weight transposes+casts + video cast in ONE dispatch ----------------
// z=0: conv_w -> cwT (B-chunked, BN=32, K=128); z=1..3: w1[i] -> w1T (BN=64, K=256);
// z=4..6: w2[i] -> w2T (BN=32, K=1024); z=7: video -> vb (A-chunked, K=128).
__global__ __launch_bounds__(256) void tcast_all_k(
        const float* __restrict__ convw, const float* __restrict__ w1,
        const float* __restrict__ w2, const float* __restrict__ video,
        bf16* __restrict__ cwT, bf16* __restrict__ w1T, bf16* __restrict__ w2T,
        bf16* __restrict__ vb) {
    const int z = blockIdx.z;
    const int tid = (int)threadIdx.x;
    if (z == 7) {   // video cast -> A-chunked vb
        const int bx = (int)blockIdx.y * 32 + (int)blockIdx.x;
        const int i = bx * 256 + tid;
        const int p = i >> 5, c0 = (i & 31) * 4;
        const float4 v = ((const float4*)video)[i];
        const size_t a0 = caddrA(CINn, p, c0);
        vb[a0 + 0] = __float2bfloat16(v.x);
        vb[a0 + 1] = __float2bfloat16(v.y);
        vb[a0 + 2] = __float2bfloat16(v.z);
        vb[a0 + 3] = __float2bfloat16(v.w);
        return;
    }
    const float* in;
    bf16* out;
    int R, C, bn;
    if (z == 0)      { in = convw;                       out = cwT;                          R = CINn; C = Cn;   bn = 32; }
    else if (z < 4)  { const int i = z - 1;
                       in = w1 + (size_t)i * Cn * 1024;  out = w1T + (size_t)i * 1024 * Cn;  R = Cn;   C = 1024; bn = 64; }
    else             { const int i = z - 4;
                       in = w2 + (size_t)i * 1024 * Cn;  out = w2T + (size_t)i * Cn * 1024;  R = 1024; C = Cn;   bn = 32; }
    if ((int)blockIdx.x >= (C >> 5) || (int)blockIdx.y >= (R >> 5)) return;

    __shared__ float tile[32][33];
    const int tx = tid & 31, ty = tid >> 5;
    const int rb = blockIdx.y << 5, cb = blockIdx.x << 5;
#pragma unroll
    for (int p = 0; p < 4; ++p)
        tile[ty + p * 8][tx] = in[(size_t)(rb + ty + p * 8) * C + cb + tx];
    __syncthreads();
    // element: n (output col dim) = cb+ty+p*8, k = rb+tx, val = tile[tx][ty+p*8]
#pragma unroll
    for (int p = 0; p < 4; ++p)
        out[caddrB(R, bn, cb + ty + p * 8, rb + tx)] = __float2bfloat16(tile[tx][ty + p * 8]);
}

// ---------------- bf16 MFMA GEMM: C[M,N] = f(A @ Wt^T + bias) ----------------
// BK=64. B always B'-chunked. A: ACH=1 -> A'-chunked, ACH=0 -> linear [m][K].
// MODE 0: Cf = v ; MODE 1: Cb = bf16(gelu(v)) in A'-chunked layout (K_next = N) ;
// MODE 2: Cf += v. Cpl: optional bf16 plane copy Cpl[c][p].
template <int BN, int MODE, int ACH>
__global__ __launch_bounds__(256) void gemm_bf16_k(
        const bf16* __restrict__ A, const bf16* __restrict__ Wt,
        const float* __restrict__ bias, float* __restrict__ Cf,
        bf16* __restrict__ Cb, bf16* __restrict__ Cpl, int M, int N, int K) {
    constexpr int BM = 128;
    constexpr int NW = BN / 2;
    constexpr int NF = BN / 32;
    constexpr int ALOADS = 4;                 // 1024 chunks / 256 threads
    constexpr int BLOADS = (BN * 8) / 256;    // 1 / 2 / 4
    __shared__ s8v As[8 * BM];
    __shared__ s8v Bs[8 * BN];

    const int tid = (int)threadIdx.x;
    const int lane = tid & 63, wid = tid >> 6;
    const int wm = wid & 1, wn = wid >> 1;
    const int l15 = lane & 15, l4 = lane >> 4;
    const int m0 = blockIdx.y * BM;
    const int n0 = blockIdx.x * BN;

    f4v acc[4][NF];
#pragma unroll
    for (int i = 0; i < 4; ++i)
#pragma unroll
        for (int j = 0; j < NF; ++j)
#pragma unroll
            for (int r = 0; r < 4; ++r) acc[i][j][r] = 0.f;

    // staging bases
    const bf16* Ach = A + ((size_t)(m0 >> 7) * (K >> 6)) * 8192;          // ACH=1
    const bf16* Aln[ALOADS];                                              // ACH=0
    if (ACH == 0) {
#pragma unroll
        for (int j = 0; j < ALOADS; ++j) {
            const int cid = j * 256 + tid;
            Aln[j] = A + (size_t)(m0 + (cid & (BM - 1))) * K + (cid / BM) * 8;
        }
    }
    const bf16* Bch = Wt + ((size_t)(n0 / BN) * (K >> 6)) * (size_t)(BN * 64);

    int kc = 0;
    for (int kb = 0; kb < K; kb += 64, ++kc) {
        if (ACH == 1) {
#pragma unroll
            for (int j = 0; j < ALOADS; ++j)
                gload_lds16(Ach + (size_t)kc * 8192 + (j * 256 + tid) * 8,
                            (bf16*)&As[j * 256 + tid]);
        } else {
#pragma unroll
            for (int j = 0; j < ALOADS; ++j)
                gload_lds16(Aln[j] + kb, (bf16*)&As[j * 256 + tid]);
        }
#pragma unroll
        for (int j = 0; j < BLOADS; ++j)
            gload_lds16(Bch + (size_t)kc * (BN * 64) + (j * 256 + tid) * 8,
                        (bf16*)&Bs[j * 256 + tid]);
        __syncthreads();

        s8v af[2][4], bfr[2][NF];
#pragma unroll
        for (int ks = 0; ks < 2; ++ks) {
#pragma unroll
            for (int i = 0; i < 4; ++i)
                af[ks][i] = As[(ks * 4 + l4) * BM + wm * 64 + i * 16 + l15];
#pragma unroll
            for (int j = 0; j < NF; ++j)
                bfr[ks][j] = Bs[(ks * 4 + l4) * BN + wn * NW + j * 16 + l15];
        }
#pragma unroll
        for (int ks = 0; ks < 2; ++ks)
#pragma unroll
            for (int i = 0; i < 4; ++i)
#pragma unroll
                for (int j = 0; j < NF; ++j)
                    acc[i][j] = __builtin_amdgcn_mfma_f32_16x16x32_bf16(
                        af[ks][i], bfr[ks][j], acc[i][j], 0, 0, 0);
        __syncthreads();
    }

#pragma unroll
    for (int i = 0; i < 4; ++i) {
        const int rbase = m0 + wm * 64 + i * 16 + l4 * 4;
#pragma unroll
        for (int j = 0; j < NF; ++j) {
            const int col = n0 + wn * NW + j * 16 + l15;
            const float bv = bias[col];
#pragma unroll
            for (int r = 0; r < 4; ++r) {
                const size_t idx = (size_t)(rbase + r) * N + col;
                float v = acc[i][j][r] + bv;
                if (MODE == 0) Cf[idx] = v;
                if (MODE == 1) Cb[caddrA(N, rbase + r, col)] = __float2bfloat16(gelu_f(v));
                if (MODE == 2) { v += Cf[idx]; Cf[idx] = v; }
                if (MODE != 1 && Cpl != nullptr)
                    Cpl[(size_t)col * Pn + rbase + r] = __float2bfloat16(v);
            }
        }
    }
}

// ---------------- fused 8-iteration depthwise circular conv SSM via MFMA ----------------
#define CLOADS(AS, BS0, BS1, body) do {                                       \
    const int bb_ = (body);                                                   \
    const int kt_ = bb_ < 7 ? 0 : (bb_ < 14 ? 1 : 2);                         \
    const int kh_ = bb_ - kt_ * 7;                                            \
    BS0 = *(const s8v*)&tw[bb_][u0][0];                                       \
    BS1 = *(const s8v*)&tw[bb_][u1][0];                                       \
    _Pragma("unroll")                                                         \
    for (int i_ = 0; i_ < 2; ++i_) {                                          \
        const int tp_ = (tout[i_] - kt_ + 9) & 7;                             \
        const int hin_ = (hl[i_] + 35 - kh_) & 31;                            \
        AS[i_] = *(const s8v*)&pl[(tp_ * 32 + hin_) * PADW + aoff];           \
    }                                                                         \
} while (0)

#define CMFMA(AS, BS0, BS1) do {                                              \
    _Pragma("unroll")                                                         \
    for (int i_ = 0; i_ < 2; ++i_) {                                          \
        acc[i_][0] = __builtin_amdgcn_mfma_f32_16x16x32_bf16(AS[i_], BS0, acc[i_][0], 0, 0, 0); \
        acc[i_][1] = __builtin_amdgcn_mfma_f32_16x16x32_bf16(AS[i_], BS1, acc[i_][1], 0, 0, 0); \
    }                                                                         \
} while (0)

__global__ __launch_bounds__(512) void conv_ssm_k(
        const bf16* __restrict__ xplb,  // [C][8192] bf16 (channel planes)
        const float* __restrict__ Ak,   // [C][147]
        const float* __restrict__ Bk,   // [C][147]
        float* __restrict__ hpo) {      // [C][8192] f32
    __shared__ __align__(16) bf16 Pl[2][256 * PADW];   // 40 KB
    __shared__ __align__(16) bf16 Tw[2][21][32][8];    // 21 KB
    __shared__ float wtap[2][NTAP];

    const int c = blockIdx.x;
    const int tid = (int)threadIdx.x;
    const int lane = tid & 63, wv = tid >> 6;
    const int l15 = lane & 15, l4 = lane >> 4;

    if (tid < NTAP) {
        wtap[0][tid] = Bk[(size_t)c * NTAP + tid];
        wtap[1][tid] = 0.9f * tanhf(Ak[(size_t)c * NTAP + tid]);
    }
    {   // stage x plane (bf16), padded rows
        const s8v* src = (const s8v*)(xplb + (size_t)c * Pn);
#pragma unroll
        for (int j = 0; j < 2; ++j) {
            const int g = j * 512 + tid;
            *(s8v*)&Pl[0][(g >> 2) * PADW + (g & 3) * 8] = src[g];
        }
    }
    __syncthreads();
    for (int e = tid; e < 2 * 21 * 32; e += 512) {
        const int sel = e / 672, rem = e % 672;
        const int body = rem >> 5, u = rem & 31;
        const float* tp = &wtap[sel][body * 7];
        bf16 row[8];
#pragma unroll
        for (int j = 0; j < 8; ++j) {
            const int kw = (u - j) & 31;
            row[j] = __float2bfloat16((kw < 7) ? tp[kw] : 0.f);
        }
        *(s8v*)&Tw[sel][body][u][0] = *(const s8v*)row;
    }

    const int u0 = (l15 - l4 * 8 + 3) & 31;
    const int u1 = (l15 + 16 - l4 * 8 + 3) & 31;
    int tout[2], hl[2];
#pragma unroll
    for (int i = 0; i < 2; ++i) {
        const int f = wv * 2 + i;
        tout[i] = f >> 1;
        hl[i] = ((f & 1) << 4) + l15;
    }
    const int aoff = l4 * 8;

    float hsum[16];
#pragma unroll
    for (int i = 0; i < 16; ++i) hsum[i] = 0.f;
    __syncthreads();

#pragma unroll 1
    for (int it = 0; it < 8; ++it) {
        const bf16* pl = Pl[it & 1];
        bf16* pd = Pl[(it + 1) & 1];
        const bf16 (*tw)[32][8] = Tw[(it == 0) ? 0 : 1];

        f4v acc[2][2];
#pragma unroll
        for (int i = 0; i < 2; ++i)
#pragma unroll
            for (int hf = 0; hf < 2; ++hf)
#pragma unroll
                for (int r = 0; r < 4; ++r) acc[i][hf][r] = 0.f;

        s8v a0[2], a1[2], b00, b01, b10, b11;
        CLOADS(a0, b00, b01, 0);
#pragma unroll 1
        for (int b = 0; b < 20; b += 2) {
            CLOADS(a1, b10, b11, b + 1);
            CMFMA(a0, b00, b01);
            CLOADS(a0, b00, b01, b + 2);
            CMFMA(a1, b10, b11);
        }
        CMFMA(a0, b00, b01);

#pragma unroll
        for (int i = 0; i < 2; ++i) {
            const int rbase = (wv * 2 + i) * 16 + l4 * 4;
#pragma unroll
            for (int hf = 0; hf < 2; ++hf) {
                const int col = l15 + hf * 16;
#pragma unroll
                for (int r = 0; r < 4; ++r) {
                    const float v = acc[i][hf][r];
                    hsum[i * 8 + hf * 4 + r] += v;
                    if (it < 7) pd[(rbase + r) * PADW + col] = __float2bfloat16(v);
                }
            }
        }
        __syncthreads();
    }

    float* o = hpo + (size_t)c * Pn;
#pragma unroll
    for (int i = 0; i < 2; ++i) {
        const int rbase = (wv * 2 + i) * 16 + l4 * 4;
#pragma unroll
        for (int hf = 0; hf < 2; ++hf)
#pragma unroll
            for (int r = 0; r < 4; ++r)
                o[(rbase + r) * 32 + l15 + hf * 16] = hsum[i * 8 + hf * 4 + r];
    }
}

// ---------------- LN from plane-layout h: x += LN(h)*s + b ; emit xb bf16 ----------------
__global__ __launch_bounds__(256) void ln_res_plane_k(
        const float* __restrict__ hpl,   // [256][8192]
        const float* __restrict__ scale, const float* __restrict__ bias,
        float* __restrict__ x,           // [8192][256] in/out
        bf16* __restrict__ xb) {         // [8192][256] linear (w1 A, ACH=0)
    __shared__ float tile[256][33];
    __shared__ float red[2][32][9];
    __shared__ float mus[32], rss[32];
    const int tid = (int)threadIdx.x;
    const int p0 = blockIdx.x << 5;

    {   // load: thread = channel
        const float* src = hpl + (size_t)tid * Pn + p0;
#pragma unroll
        for (int j = 0; j < 32; j += 4) {
            const float4 v = *(const float4*)(src + j);
            tile[tid][j] = v.x; tile[tid][j + 1] = v.y;
            tile[tid][j + 2] = v.z; tile[tid][j + 3] = v.w;
        }
    }
    __syncthreads();
    {   // partial reduce: tid = g*32 + p
        const int p = tid & 31, g = tid >> 5;
        float s = 0.f, ss = 0.f;
#pragma unroll
        for (int ci = 0; ci < 32; ++ci) {
            const float v = tile[g * 32 + ci][p];
            s += v; ss += v * v;
        }
        red[0][p][g] = s; red[1][p][g] = ss;
    }
    __syncthreads();
    if (tid < 32) {
        float s = 0.f, ss = 0.f;
#pragma unroll
        for (int g = 0; g < 8; ++g) { s += red[0][tid][g]; ss += red[1][tid][g]; }
        const float mu = s * (1.0f / 256.0f);
        const float var = ss * (1.0f / 256.0f) - mu * mu;
        mus[tid] = mu;
        rss[tid] = rsqrtf(var + 1e-6f);
    }
    __syncthreads();
    {   // apply: thread = channel, coalesced across lanes per point
        const int cch = tid;
        const float sc = scale[cch], bi = bias[cch];
#pragma unroll 4
        for (int j = 0; j < 32; ++j) {
            const size_t idx = (size_t)(p0 + j) * Cn + cch;
            const float normed = (tile[cch][j] - mus[j]) * rss[j] * sc + bi;
            const float xv = x[idx] + normed;
            x[idx] = xv;
            xb[idx] = __float2bfloat16(xv);
        }
    }
}

// ---------------- feat partial sums over (h,w) ----------------
__global__ void feat_part_k(const float* __restrict__ x, float* __restrict__ part) {
    const int t = blockIdx.x, sgm = blockIdx.y;
    const int c = (int)threadIdx.x;
    float acc = 0.f;
    const float* xp_ = x + ((size_t)t * 1024 + sgm * 128) * Cn + c;
    for (int p = 0; p < 128; ++p) acc += xp_[(size_t)p * Cn];
    part[(t * 8 + sgm) * Cn + c] = acc;
}

// ---------------- heads (folds the feat 8-way reduce) ----------------
__global__ __launch_bounds__(256) void heads_k(
        const float* __restrict__ part, const float* __restrict__ qp,
        const float* __restrict__ traj_w, const float* __restrict__ traj_b,
        const float* __restrict__ occ_w, const float* __restrict__ occ_b,
        float* __restrict__ out) {
    __shared__ float fs[Tn * Cn];
    __shared__ float proj[Tn][3];
    const int tid = (int)threadIdx.x;
    for (int i = tid; i < Tn * Cn; i += 256) {
        const int t = i >> 8, c = i & 255;
        float s = 0.f;
#pragma unroll
        for (int j = 0; j < 8; ++j) s += part[(t * 8 + j) * Cn + c];
        fs[i] = s * (1.0f / 1024.0f);
    }
    __syncthreads();
    if (tid < 24) {
        const int t = tid / 3, j = tid % 3;
        float s = 0.f;
        for (int c = 0; c < Cn; ++c) {
            const float w = (j < 2) ? traj_w[c * 2 + j] : occ_w[c];
            s += fs[t * Cn + c] * w;
        }
        s += (j < 2) ? traj_b[j] : occ_b[0];
        proj[t][j] = s;
    }
    __syncthreads();
    const int n = tid;
#pragma unroll
    for (int t = 0; t < Tn; ++t) {
        out[(n * Tn + t) * 2 + 0] = proj[t][0] + qp[n * 3 + 1];
        out[(n * Tn + t) * 2 + 1] = proj[t][1] + qp[n * 3 + 2];
        out[4096 + n * Tn + t] = 1.0f / (1.0f + expf(-proj[t][2]));
    }
}

extern "C" void kernel_launch(void* const* d_in, const int* in_sizes, int n_in,
                              void* d_out, int out_size, void* d_ws, size_t ws_size,
                              hipStream_t stream) {
    const float* video = (const float*)d_in[0];
    const float* qp    = (const float*)d_in[1];
    const float* convw = (const float*)d_in[2];
    const float* convb = (const float*)d_in[3];
    const float* Ak    = (const float*)d_in[4];
    const float* Bk    = (const float*)d_in[5];
    const float* ln_s  = (const float*)d_in[6];
    const float* ln_b  = (const float*)d_in[7];
    const float* w1    = (const float*)d_in[8];
    const float* b1    = (const float*)d_in[9];
    const float* w2    = (const float*)d_in[10];
    const float* b2    = (const float*)d_in[11];
    const float* tw    = (const float*)d_in[12];
    const float* tb    = (const float*)d_in[13];
    const float* ow    = (const float*)d_in[14];
    const float* ob    = (const float*)d_in[15];

    char* wsb = (char*)d_ws;
    float* x    = (float*)wsb;           wsb += (size_t)Pn * Cn * 4;
    float* hpl  = (float*)wsb;           wsb += (size_t)Pn * Cn * 4;
    bf16*  xplb = (bf16*)wsb;            wsb += (size_t)Pn * Cn * 2;
    bf16*  xb   = (bf16*)wsb;            wsb += (size_t)Pn * Cn * 2;
    bf16*  mb   = (bf16*)wsb;            wsb += (size_t)Pn * 1024 * 2;
    bf16*  vb   = (bf16*)wsb;            wsb += (size_t)Pn * CINn * 2;
    bf16*  cwT  = (bf16*)wsb;            wsb += (size_t)Cn * CINn * 2;
    bf16*  w1T  = (bf16*)wsb;            wsb += (size_t)3 * 1024 * Cn * 2;
    bf16*  w2T  = (bf16*)wsb;            wsb += (size_t)3 * Cn * 1024 * 2;
    float* part = (float*)wsb;           wsb += (size_t)64 * Cn * 4;

    tcast_all_k<<<dim3(32, 32, 8), 256, 0, stream>>>(convw, w1, w2, video,
                                                     cwT, w1T, w2T, vb);

    // x = video @ conv_w + b ; also emit bf16 planes for conv input
    gemm_bf16_k<32, 0, 1><<<dim3(Cn / 32, Pn / 128), 256, 0, stream>>>(
        vb, cwT, convb, x, nullptr, xplb, Pn, Cn, CINn);

    for (int i = 0; i < 3; ++i) {
        conv_ssm_k<<<Cn, 512, 0, stream>>>(xplb, Ak + (size_t)i * Cn * NTAP,
                                           Bk + (size_t)i * Cn * NTAP, hpl);
        ln_res_plane_k<<<Pn / 32, 256, 0, stream>>>(hpl, ln_s + i * Cn,
                                                    ln_b + i * Cn, x, xb);
        // m = gelu(xb @ w1)  (A linear, B chunked; mb written A-chunked for w2)
        gemm_bf16_k<64, 1, 0><<<dim3(1024 / 64, Pn / 128), 256, 0, stream>>>(
            xb, w1T + (size_t)i * 1024 * Cn, b1 + (size_t)i * 1024, nullptr, mb,
            nullptr, Pn, 1024, Cn);
        // x += m @ w2  (A chunked, B chunked)
        gemm_bf16_k<32, 2, 1><<<dim3(Cn / 32, Pn / 128), 256, 0, stream>>>(
            mb, w2T + (size_t)i * Cn * 1024, b2 + (size_t)i * Cn, x, nullptr,
            (i < 2) ? xplb : nullptr, Pn, Cn, 1024);
    }

    feat_part_k<<<dim3(Tn, 8), 256, 0, stream>>>(x, part);
    heads_k<<<1, 256, 0, stream>>>(part, qp, tw, tb, ow, ob, (float*)d_out);
}